// Round 13
// baseline (2068.085 us; speedup 1.0000x reference)
//
#include <hip/hip_runtime.h>
#include <hip/hip_bf16.h>
#include <math.h>

// ---- problem constants ----
#define Bc 4
#define Sc 1024
#define Dc 768
#define Hc 12
#define Lc 12
#define FFc 3072
#define Mtot (Bc*Sc)   // 4096 rows

typedef __bf16 bf16x8 __attribute__((ext_vector_type(8)));
typedef float f32x4 __attribute__((ext_vector_type(4)));

__device__ __forceinline__ void gload_lds16(const void* g, void* l) {
    __builtin_amdgcn_global_load_lds((const __attribute__((address_space(1))) void*)g,
                                     (__attribute__((address_space(3))) void*)l, 16, 0, 0);
}

template <int N>
__device__ __forceinline__ void waitcnt_vm() {
    if constexpr (N == 0)       asm volatile("s_waitcnt vmcnt(0)" ::: "memory");
    else if constexpr (N == 4)  asm volatile("s_waitcnt vmcnt(4)" ::: "memory");
    else if constexpr (N == 5)  asm volatile("s_waitcnt vmcnt(5)" ::: "memory");
    else if constexpr (N == 8)  asm volatile("s_waitcnt vmcnt(8)" ::: "memory");
    else if constexpr (N == 10) asm volatile("s_waitcnt vmcnt(10)" ::: "memory");
    else static_assert(N == 0, "unsupported vmcnt");
}

// =====================================================================
// Embedding: x[b,s,:] = wte[tok] + wpe[s]
__global__ __launch_bounds__(256) void embed_kernel(const int* __restrict__ tokens,
                                                    const float* __restrict__ wte,
                                                    const float* __restrict__ wpe,
                                                    float* __restrict__ x) {
    int row = blockIdx.x;
    int s = row & (Sc - 1);
    int tok = tokens[row];
    const float* wt = wte + (size_t)tok * Dc;
    const float* wp = wpe + (size_t)s * Dc;
    float* xr = x + (size_t)row * Dc;
#pragma unroll
    for (int k = 0; k < 3; ++k) {
        int d = threadIdx.x + k * 256;
        xr[d] = wt[d] + wp[d];
    }
}

// =====================================================================
// Per-layer prep, one dispatch: blocks 0..6911 transpose the 4 weights;
// blocks 6912.. do LN1. SUMIN: x = xin0 + xin1 (split-K partials) is
// materialized to xout; else reads xin0 directly.
template <bool SUMIN>
__global__ __launch_bounds__(256) void prep_kernel(
        const float* __restrict__ We, const float* __restrict__ Wo,
        const float* __restrict__ Wf1, const float* __restrict__ Wf2,
        __bf16* __restrict__ Te, __bf16* __restrict__ To,
        __bf16* __restrict__ Tf1, __bf16* __restrict__ Tf2,
        const float* __restrict__ xin0, const float* __restrict__ xin1,
        float* __restrict__ xout,
        const float* __restrict__ lw, const float* __restrict__ lb,
        __bf16* __restrict__ outb) {
    __shared__ float shm[32 * 33];
    int bid = blockIdx.x;
    if (bid < 6912) {
        const float* W; __bf16* T; int K, N, t;
        if (bid < 1728)      { W = We;  T = Te;  K = 768;  N = 2304; t = bid; }
        else if (bid < 2304) { W = Wo;  T = To;  K = 768;  N = 768;  t = bid - 1728; }
        else if (bid < 4608) { W = Wf1; T = Tf1; K = 768;  N = 3072; t = bid - 2304; }
        else                 { W = Wf2; T = Tf2; K = 3072; N = 768;  t = bid - 4608; }
        int nx = N >> 5;
        int n0 = (t % nx) * 32, k0 = (t / nx) * 32;
        int tx = threadIdx.x & 31, ty = threadIdx.x >> 5;   // ty 0..7
#pragma unroll
        for (int i = 0; i < 4; ++i)
            shm[(ty + 8 * i) * 33 + tx] = W[(size_t)(k0 + ty + 8 * i) * N + n0 + tx];
        __syncthreads();
#pragma unroll
        for (int i = 0; i < 4; ++i)
            T[(size_t)(n0 + ty + 8 * i) * K + k0 + tx] = (__bf16)shm[tx * 33 + ty + 8 * i];
    } else {
        int row = bid - 6912;
        size_t ro = (size_t)row * Dc;
        int t = threadIdx.x;
        float v0, v1, v2;
        if (SUMIN) {
            v0 = xin0[ro + t]       + xin1[ro + t];
            v1 = xin0[ro + t + 256] + xin1[ro + t + 256];
            v2 = xin0[ro + t + 512] + xin1[ro + t + 512];
            xout[ro + t] = v0; xout[ro + t + 256] = v1; xout[ro + t + 512] = v2;
        } else {
            v0 = xin0[ro + t]; v1 = xin0[ro + t + 256]; v2 = xin0[ro + t + 512];
        }
        float s1 = v0 + v1 + v2;
        float s2 = v0 * v0 + v1 * v1 + v2 * v2;
#pragma unroll
        for (int o = 32; o; o >>= 1) {
            s1 += __shfl_down(s1, o);
            s2 += __shfl_down(s2, o);
        }
        int wv = t >> 6;
        if ((t & 63) == 0) { shm[wv] = s1; shm[4 + wv] = s2; }
        __syncthreads();
        float S1 = shm[0] + shm[1] + shm[2] + shm[3];
        float S2 = shm[4] + shm[5] + shm[6] + shm[7];
        float mean = S1 * (1.0f / Dc);
        float var = S2 * (1.0f / Dc) - mean * mean;
        float rs = rsqrtf(var + 1e-5f);
        outb[ro + t]       = (__bf16)((v0 - mean) * rs * lw[t]       + lb[t]);
        outb[ro + t + 256] = (__bf16)((v1 - mean) * rs * lw[t + 256] + lb[t + 256]);
        outb[ro + t + 512] = (__bf16)((v2 - mean) * rs * lw[t + 512] + lb[t + 512]);
    }
}

// =====================================================================
// LayerNorm (LN2): input = xin0 + xin1 (split-K partials), bf16 + f32 out
__global__ __launch_bounds__(256) void ln2_kernel(const float* __restrict__ xin0,
                                                  const float* __restrict__ xin1,
                                                  const float* __restrict__ lw,
                                                  const float* __restrict__ lb,
                                                  __bf16* __restrict__ outb,
                                                  float* __restrict__ outf) {
    int row = blockIdx.x;
    size_t ro = (size_t)row * Dc;
    int t = threadIdx.x;
    float v0 = xin0[ro + t]       + xin1[ro + t];
    float v1 = xin0[ro + t + 256] + xin1[ro + t + 256];
    float v2 = xin0[ro + t + 512] + xin1[ro + t + 512];
    float s1 = v0 + v1 + v2;
    float s2 = v0 * v0 + v1 * v1 + v2 * v2;
    __shared__ float red[8];
#pragma unroll
    for (int o = 32; o; o >>= 1) {
        s1 += __shfl_down(s1, o);
        s2 += __shfl_down(s2, o);
    }
    int wv = t >> 6;
    if ((t & 63) == 0) { red[wv] = s1; red[4 + wv] = s2; }
    __syncthreads();
    float S1 = red[0] + red[1] + red[2] + red[3];
    float S2 = red[4] + red[5] + red[6] + red[7];
    float mean = S1 * (1.0f / Dc);
    float var = S2 * (1.0f / Dc) - mean * mean;
    float rs = rsqrtf(var + 1e-5f);
    float o0 = (v0 - mean) * rs * lw[t]       + lb[t];
    float o1 = (v1 - mean) * rs * lw[t + 256] + lb[t + 256];
    float o2 = (v2 - mean) * rs * lw[t + 512] + lb[t + 512];
    outb[ro + t]       = (__bf16)o0;
    outb[ro + t + 256] = (__bf16)o1;
    outb[ro + t + 512] = (__bf16)o2;
    outf[ro + t]       = o0;
    outf[ro + t + 256] = o1;
    outf[ro + t + 512] = o2;
}

// =====================================================================
// finalize: out = a + b (f32, float4)
__global__ __launch_bounds__(256) void finalize_kernel(const float* __restrict__ a,
                                                       const float* __restrict__ b,
                                                       float* __restrict__ out) {
    size_t idx = ((size_t)blockIdx.x * 256 + threadIdx.x) * 4;
    float4 va = *(const float4*)(a + idx);
    float4 vb = *(const float4*)(b + idx);
    float4 o = make_float4(va.x + vb.x, va.y + vb.y, va.z + vb.z, va.w + vb.w);
    *(float4*)(out + idx) = o;
}

// =====================================================================
// bf16 MFMA GEMM, both operands row-major-K (B pre-transposed).
// NBUF=3: 2-deep counted-vmcnt pipeline (wide GEMMs, 3 blocks/CU).
// NBUF=2: 1-deep pipeline, 40KB LDS -> 4 blocks/CU (narrow split-K GEMMs).
// SPLIT: gridDim.z=2 K-chunks; chunk0 = full epilogue (bias+addin->Cf),
//        chunk1 = raw f32 partial -> Cf2. K = chunk length, Kst = row stride.
// EPI: 1 = bias + addin -> f32 Cf ; 2 = bias + gelu -> bf16 Cb ;
//      3 = QKV (bf16 Cb + presents)
template <int BMr, int BNc, int BK, int EPI, int NBUF, bool SPLIT>
__global__ __launch_bounds__(256) void gemm_bf16(const __bf16* __restrict__ A,
                                                 const __bf16* __restrict__ BT,
                                                 const float* __restrict__ bias,
                                                 const float* __restrict__ addin,
                                                 float* __restrict__ Cf,
                                                 float* __restrict__ Cf2,
                                                 __bf16* __restrict__ Cb,
                                                 float* __restrict__ pres,
                                                 int K, int Kst, int N) {
    constexpr int HRm = BMr / 32, HRn = BNc / 32;
    constexpr int KS  = BK / 32;
    constexpr int LPR = BK / 8;
    constexpr int SSH = (BK == 32) ? 1 : 0;
    constexpr int IA  = BMr * BK / 2048;
    constexpr int IB  = BNc * BK / 2048;
    constexpr int S1w = IA + IB;
    static_assert(IA * 2048 == BMr * BK && IB * 2048 == BNc * BK, "staging granularity");
    __shared__ __bf16 As[NBUF][BMr * BK];
    __shared__ __bf16 Bs[NBUF][BNc * BK];
    int tid = threadIdx.x;
    int w = tid >> 6, l = tid & 63;
    int wrow = (w >> 1) * (BMr / 2), wcol = (w & 1) * (BNc / 2);
    int brow0 = blockIdx.x * BMr, bcol0 = blockIdx.y * BNc;
    int koff = SPLIT ? blockIdx.z * K : 0;
    int rsel = l & 15, lg = l >> 4;

    f32x4 acc[HRm][HRn] = {};

    const __bf16* Abase = A + (size_t)brow0 * Kst + koff;
    const __bf16* Bbase = BT + (size_t)bcol0 * Kst + koff;

    auto stage = [&](int buf, int kt) {
#pragma unroll
        for (int i = 0; i < IA; ++i) {
            int cid = i * 256 + tid;
            int row = cid / LPR, slot = cid % LPR;
            int chunk = slot ^ ((row >> SSH) & (LPR - 1));
            gload_lds16(Abase + (size_t)row * Kst + kt + chunk * 8,
                        &As[buf][(i * 256 + w * 64) * 8]);
        }
#pragma unroll
        for (int i = 0; i < IB; ++i) {
            int cid = i * 256 + tid;
            int row = cid / LPR, slot = cid % LPR;
            int chunk = slot ^ ((row >> SSH) & (LPR - 1));
            gload_lds16(Bbase + (size_t)row * Kst + kt + chunk * 8,
                        &Bs[buf][(i * 256 + w * 64) * 8]);
        }
    };

    int nk = K / BK;
    stage(0, 0);
    if (NBUF == 3) stage(1, BK);
    int cur = 0;
    for (int kt = 0; kt < nk; ++kt) {
        if (NBUF == 3) {
            if (kt + 2 < nk) {
                int b2 = cur + 2; if (b2 >= 3) b2 -= 3;
                stage(b2, (kt + 2) * BK);
                waitcnt_vm<2 * S1w>();
            } else if (kt + 1 < nk) {
                waitcnt_vm<S1w>();
            } else {
                waitcnt_vm<0>();
            }
        } else {
            if (kt + 1 < nk) {
                stage(cur ^ 1, (kt + 1) * BK);
                waitcnt_vm<S1w>();
            } else {
                waitcnt_vm<0>();
            }
        }
        __builtin_amdgcn_s_barrier();
        __builtin_amdgcn_sched_barrier(0);

        bf16x8 af[KS][HRm], bfr[KS][HRn];
#pragma unroll
        for (int m = 0; m < HRm; ++m) {
            int r = wrow + m * 16 + rsel;
            int sw = (r >> SSH) & (LPR - 1);
#pragma unroll
            for (int s = 0; s < KS; ++s)
                af[s][m] = *(const bf16x8*)(&As[cur][r * BK + ((s * 4 + lg) ^ sw) * 8]);
        }
#pragma unroll
        for (int n = 0; n < HRn; ++n) {
            int r = wcol + n * 16 + rsel;
            int sw = (r >> SSH) & (LPR - 1);
#pragma unroll
            for (int s = 0; s < KS; ++s)
                bfr[s][n] = *(const bf16x8*)(&Bs[cur][r * BK + ((s * 4 + lg) ^ sw) * 8]);
        }
#pragma unroll
        for (int s = 0; s < KS; ++s)
#pragma unroll
            for (int m = 0; m < HRm; ++m)
#pragma unroll
                for (int n = 0; n < HRn; ++n)
                    acc[m][n] = __builtin_amdgcn_mfma_f32_16x16x32_bf16(af[s][m], bfr[s][n], acc[m][n], 0, 0, 0);

        __builtin_amdgcn_sched_barrier(0);
        __builtin_amdgcn_s_barrier();
        if (NBUF == 3) { cur = (cur == 2) ? 0 : cur + 1; } else { cur ^= 1; }
    }

    // epilogue: frag C[row=lg*4+i][col=rsel]
    int r4 = lg * 4, cc = rsel;
    bool rawpart = SPLIT && (blockIdx.z == 1);
#pragma unroll
    for (int m = 0; m < HRm; ++m)
#pragma unroll
        for (int n = 0; n < HRn; ++n) {
            int col = bcol0 + wcol + n * 16 + cc;
            float bv = rawpart ? 0.0f : bias[col];
#pragma unroll
            for (int i = 0; i < 4; ++i) {
                int row = brow0 + wrow + m * 16 + r4 + i;
                float v = acc[m][n][i];
                if (rawpart) {
                    Cf2[(size_t)row * N + col] = v;
                    continue;
                }
                v += bv;
                if (EPI == 1) {
                    v += addin[(size_t)row * N + col];
                    Cf[(size_t)row * N + col] = v;
                }
                if (EPI == 2) {
                    float u = 0.7978845608f * (v + 0.044715f * v * v * v);
                    v = v / (1.0f + __expf(-2.0f * u));
                    Cb[(size_t)row * N + col] = (__bf16)v;
                }
                if (EPI == 3) {
                    Cb[(size_t)row * N + col] = (__bf16)v;
                    if (col >= 768) {
                        int kv = (col >= 1536) ? 1 : 0;
                        pres[((size_t)kv * Mtot + row) * Dc + (col - 768 - kv * 768)] = v;
                    }
                }
            }
        }
}

// =====================================================================
// MFMA flash attention. Block = 4 waves, 64 q-rows for one (b,h). bf16 out.
__global__ __launch_bounds__(256) void attn_mfma_kernel(const __bf16* __restrict__ qkvb,
                                                        __bf16* __restrict__ aout) {
    __shared__ __bf16 Ks[64 * 72];
    __shared__ __bf16 Vts[64 * 72];
    __shared__ __bf16 Ps[4][16 * 72];
    int bh = blockIdx.x;
    int b = bh / Hc, h = bh % Hc;
    int qt = (Sc / 64 - 1) - blockIdx.y;
    int tid = threadIdx.x;
    int w = tid >> 6, l = tid & 63;
    int lr = l & 15, lg = l >> 4;
    int qb = qt * 64;

    const __bf16* base = qkvb + (size_t)b * Sc * 2304 + h * 64;

    bf16x8 qf[2];
    {
        const __bf16* qrow = base + (size_t)(qb + w * 16 + lr) * 2304 + lg * 8;
        qf[0] = *(const bf16x8*)(qrow);
        qf[1] = *(const bf16x8*)(qrow + 32);
    }

    f32x4 O[4] = {};
    float mrow[4], lrowv[4];
#pragma unroll
    for (int i = 0; i < 4; ++i) { mrow[i] = -1e30f; lrowv[i] = 0.0f; }

    int kj = tid >> 2, kc = tid & 3;
    int vj = tid & 63, vd0 = (tid >> 6) * 8;

    for (int t = 0; t <= qt; ++t) {
        __syncthreads();
#pragma unroll
        for (int it = 0; it < 2; ++it) {
            int c = kc + 4 * it;
            bf16x8 v = *(const bf16x8*)(base + (size_t)(t * 64 + kj) * 2304 + 768 + c * 8);
            *(bf16x8*)(&Ks[kj * 72 + c * 8]) = v;
        }
#pragma unroll
        for (int it = 0; it < 2; ++it) {
            int d0 = vd0 + 32 * it;
            bf16x8 v = *(const bf16x8*)(base + (size_t)(t * 64 + vj) * 2304 + 1536 + d0);
#pragma unroll
            for (int i = 0; i < 8; ++i)
                Vts[(d0 + i) * 72 + vj] = v[i];
        }
        __syncthreads();

        f32x4 sc[4] = {};
        __builtin_amdgcn_s_setprio(1);
#pragma unroll
        for (int s = 0; s < 2; ++s)
#pragma unroll
            for (int n = 0; n < 4; ++n) {
                bf16x8 kf = *(const bf16x8*)(&Ks[(n * 16 + lr) * 72 + s * 32 + lg * 8]);
                sc[n] = __builtin_amdgcn_mfma_f32_16x16x32_bf16(qf[s], kf, sc[n], 0, 0, 0);
            }
        __builtin_amdgcn_s_setprio(0);

        bool diag = (t == qt);
#pragma unroll
        for (int n = 0; n < 4; ++n)
#pragma unroll
            for (int i = 0; i < 4; ++i) {
                float s = sc[n][i] * 0.125f;
                if (diag) {
                    int jg = n * 16 + lr;
                    int qg = w * 16 + lg * 4 + i;
                    if (jg > qg) s = -1e30f;
                }
                sc[n][i] = s;
            }
        float corr[4], psum[4];
#pragma unroll
        for (int i = 0; i < 4; ++i) {
            float mx = fmaxf(fmaxf(sc[0][i], sc[1][i]), fmaxf(sc[2][i], sc[3][i]));
#pragma unroll
            for (int o = 1; o < 16; o <<= 1) mx = fmaxf(mx, __shfl_xor(mx, o));
            float mnew = fmaxf(mrow[i], mx);
            corr[i] = __expf(mrow[i] - mnew);
            mrow[i] = mnew;
            psum[i] = 0.0f;
        }
#pragma unroll
        for (int n = 0; n < 4; ++n)
#pragma unroll
            for (int i = 0; i < 4; ++i) {
                float p = __expf(sc[n][i] - mrow[i]);
                psum[i] += p;
                Ps[w][(lg * 4 + i) * 72 + n * 16 + lr] = (__bf16)p;
            }
#pragma unroll
        for (int i = 0; i < 4; ++i) {
#pragma unroll
            for (int o = 1; o < 16; o <<= 1) psum[i] += __shfl_xor(psum[i], o);
            lrowv[i] = lrowv[i] * corr[i] + psum[i];
        }
#pragma unroll
        for (int n = 0; n < 4; ++n)
#pragma unroll
            for (int i = 0; i < 4; ++i) O[n][i] *= corr[i];
        __builtin_amdgcn_s_setprio(1);
#pragma unroll
        for (int s = 0; s < 2; ++s) {
            bf16x8 pf = *(const bf16x8*)(&Ps[w][lr * 72 + s * 32 + lg * 8]);
#pragma unroll
            for (int n = 0; n < 4; ++n) {
                bf16x8 vf = *(const bf16x8*)(&Vts[(n * 16 + lr) * 72 + s * 32 + lg * 8]);
                O[n] = __builtin_amdgcn_mfma_f32_16x16x32_bf16(pf, vf, O[n], 0, 0, 0);
            }
        }
        __builtin_amdgcn_s_setprio(0);
    }
    __bf16* orow = aout + (size_t)(b * Sc + qb + w * 16 + lg * 4) * Dc + h * 64 + lr;
#pragma unroll
    for (int n = 0; n < 4; ++n)
#pragma unroll
        for (int i = 0; i < 4; ++i)
            orow[(size_t)i * Dc + n * 16] = (__bf16)(O[n][i] / lrowv[i]);
}

// =====================================================================
extern "C" void kernel_launch(void* const* d_in, const int* in_sizes, int n_in,
                              void* d_out, int out_size, void* d_ws, size_t ws_size,
                              hipStream_t stream) {
    const int*   tokens = (const int*)d_in[0];
    const float* wte    = (const float*)d_in[1];
    const float* wpe    = (const float*)d_in[2];
    const float* ln1_w  = (const float*)d_in[3];
    const float* ln1_b  = (const float*)d_in[4];
    const float* ln2_w  = (const float*)d_in[5];
    const float* ln2_b  = (const float*)d_in[6];
    const float* W_exp  = (const float*)d_in[7];
    const float* b_exp  = (const float*)d_in[8];
    const float* W_o    = (const float*)d_in[9];
    const float* b_o    = (const float*)d_in[10];
    const float* W_ff1  = (const float*)d_in[11];
    const float* b_ff1  = (const float*)d_in[12];
    const float* W_ff2  = (const float*)d_in[13];
    const float* b_ff2  = (const float*)d_in[14];

    float* out_x    = (float*)d_out;
    float* out_pres = out_x + (size_t)Mtot * Dc;

    float* ws   = (float*)d_ws;
    float* x    = ws;                                   // M*D f32 (residual / W_o p0)
    float* addf = x + (size_t)Mtot * Dc;                // M*D f32 (LN2 out / FF2 p0)
    float* p1w  = addf + (size_t)Mtot * Dc;             // M*D f32 (W_o partial 1)
    float* q1   = p1w + (size_t)Mtot * Dc;              // M*D f32 (FF2 partial 1)
    __bf16* hb   = (__bf16*)(q1 + (size_t)Mtot * Dc);   // M*D bf16 (LN1 out / attn out)
    __bf16* addb = hb + (size_t)Mtot * Dc;              // M*D bf16 (LN2 out)
    __bf16* qkvb = addb + (size_t)Mtot * Dc;            // M*3D bf16
    __bf16* ff1b = qkvb + (size_t)Mtot * 3 * Dc;        // M*FF bf16
    __bf16* wt_exp = ff1b + (size_t)Mtot * FFc;         // 2304*768
    __bf16* wt_o   = wt_exp + (size_t)2304 * 768;       // 768*768
    __bf16* wt_ff1 = wt_o   + (size_t)768 * 768;        // 3072*768
    __bf16* wt_ff2 = wt_ff1 + (size_t)3072 * 768;       // 768*3072

    embed_kernel<<<Mtot, 256, 0, stream>>>(tokens, wte, wpe, x);

    for (int lidx = 0; lidx < Lc; ++lidx) {
        // fused per-layer prep: 4 weight transposes + LN1 (one dispatch).
        // From layer 1 on, LN1 input = addf + q1 (FF2 split partials), and
        // x is materialized here.
        if (lidx == 0) {
            prep_kernel<false><<<6912 + Mtot, 256, 0, stream>>>(
                W_exp, W_o, W_ff1, W_ff2, wt_exp, wt_o, wt_ff1, wt_ff2,
                x, nullptr, nullptr, ln1_w, ln1_b, hb);
        } else {
            prep_kernel<true><<<6912 + Mtot, 256, 0, stream>>>(
                W_exp + (size_t)lidx * 768 * 2304, W_o + (size_t)lidx * 768 * 768,
                W_ff1 + (size_t)lidx * 768 * 3072, W_ff2 + (size_t)lidx * 3072 * 768,
                wt_exp, wt_o, wt_ff1, wt_ff2,
                addf, q1, x, ln1_w + lidx * Dc, ln1_b + lidx * Dc, hb);
        }

        // QKV = hb @ W_exp + b_exp -> qkvb bf16 + presents f32  (768 blocks = 3/CU)
        gemm_bf16<64, 192, 32, 3, 3, false><<<dim3(Mtot / 64, 2304 / 192), 256, 0, stream>>>(
            hb, wt_exp, b_exp + (size_t)lidx * 3 * Dc,
            nullptr, nullptr, nullptr, qkvb,
            out_pres + (size_t)lidx * 2 * Mtot * Dc, 768, 768, 2304);
        // attention -> hb (bf16)
        attn_mfma_kernel<<<dim3(Bc * Hc, Sc / 64), 256, 0, stream>>>(qkvb, hb);
        // W_o split-K x2: chunk0 -> x (in place, + b_o + x_old), chunk1 -> p1w
        // 1024 blocks = 4/CU (2-buffer, 40KB LDS)
        gemm_bf16<64, 96, 64, 1, 2, true><<<dim3(Mtot / 64, 768 / 96, 2), 256, 0, stream>>>(
            hb, wt_o, b_o + (size_t)lidx * Dc,
            x, x, p1w, nullptr, nullptr, 384, 768, 768);
        // LN2 on (x + p1w) -> addb bf16 + addf f32
        ln2_kernel<<<Mtot, 256, 0, stream>>>(
            x, p1w, ln2_w + lidx * Dc, ln2_b + lidx * Dc, addb, addf);
        // ff1 = gelu(addb @ W_ff1 + b_ff1) -> bf16  (128x128, 768 blocks = 3/CU)
        gemm_bf16<128, 128, 32, 2, 3, false><<<dim3(Mtot / 128, FFc / 128), 256, 0, stream>>>(
            addb, wt_ff1, b_ff1 + (size_t)lidx * FFc,
            nullptr, nullptr, nullptr, ff1b, nullptr, 768, 768, FFc);
        // FF2 split-K x2: chunk0 -> addf (in place, + b_ff2 + addf), chunk1 -> q1
        gemm_bf16<64, 96, 64, 1, 2, true><<<dim3(Mtot / 64, 768 / 96, 2), 256, 0, stream>>>(
            ff1b, wt_ff2, b_ff2 + (size_t)lidx * Dc,
            addf, addf, q1, nullptr, nullptr, 1536, 3072, 768);
    }

    // final layer output: out_x = addf + q1
    finalize_kernel<<<(Mtot * Dc) / 1024, 256, 0, stream>>>(addf, q1, out_x);
}

// Round 14
// 2020.048 us; speedup vs baseline: 1.0238x; 1.0238x over previous
//
#include <hip/hip_runtime.h>
#include <hip/hip_bf16.h>
#include <math.h>

// ---- problem constants ----
#define Bc 4
#define Sc 1024
#define Dc 768
#define Hc 12
#define Lc 12
#define FFc 3072
#define Mtot (Bc*Sc)   // 4096 rows

typedef __bf16 bf16x8 __attribute__((ext_vector_type(8)));
typedef __bf16 bf16x4 __attribute__((ext_vector_type(4)));
typedef float f32x4 __attribute__((ext_vector_type(4)));

__device__ __forceinline__ void gload_lds16(const void* g, void* l) {
    __builtin_amdgcn_global_load_lds((const __attribute__((address_space(1))) void*)g,
                                     (__attribute__((address_space(3))) void*)l, 16, 0, 0);
}

template <int N>
__device__ __forceinline__ void waitcnt_vm() {
    if constexpr (N == 0)       asm volatile("s_waitcnt vmcnt(0)" ::: "memory");
    else if constexpr (N == 4)  asm volatile("s_waitcnt vmcnt(4)" ::: "memory");
    else if constexpr (N == 5)  asm volatile("s_waitcnt vmcnt(5)" ::: "memory");
    else if constexpr (N == 8)  asm volatile("s_waitcnt vmcnt(8)" ::: "memory");
    else if constexpr (N == 10) asm volatile("s_waitcnt vmcnt(10)" ::: "memory");
    else static_assert(N == 0, "unsupported vmcnt");
}

// =====================================================================
// Embedding: x[b,s,:] = wte[tok] + wpe[s]
__global__ __launch_bounds__(256) void embed_kernel(const int* __restrict__ tokens,
                                                    const float* __restrict__ wte,
                                                    const float* __restrict__ wpe,
                                                    float* __restrict__ x) {
    int row = blockIdx.x;
    int s = row & (Sc - 1);
    int tok = tokens[row];
    const float* wt = wte + (size_t)tok * Dc;
    const float* wp = wpe + (size_t)s * Dc;
    float* xr = x + (size_t)row * Dc;
#pragma unroll
    for (int k = 0; k < 3; ++k) {
        int d = threadIdx.x + k * 256;
        xr[d] = wt[d] + wp[d];
    }
}

// =====================================================================
// Per-layer prep, one dispatch:
//   blocks 0..1727: transpose the 4 weights (f32 [K][N] -> bf16 [N][K]),
//   64x64 tiles, float4 loads, ushort4 (bf16x4) stores.
//   blocks 1728..1728+4095: LN1 row (bid-1728), float4/bf16x4 vectorized.
// Segments: exp 432 (36x12), o 144 (12x12), ff1 576 (48x12), ff2 576 (12x48).
__global__ __launch_bounds__(256) void prep_kernel(
        const float* __restrict__ We, const float* __restrict__ Wo,
        const float* __restrict__ Wf1, const float* __restrict__ Wf2,
        __bf16* __restrict__ Te, __bf16* __restrict__ To,
        __bf16* __restrict__ Tf1, __bf16* __restrict__ Tf2,
        const float* __restrict__ x, const float* __restrict__ lw,
        const float* __restrict__ lb, __bf16* __restrict__ outb) {
    __shared__ float shm[64 * 69];
    int bid = blockIdx.x;
    int t = threadIdx.x;
    if (bid < 1728) {
        const float* W; __bf16* T; int K, N, tt;
        if (bid < 432)       { W = We;  T = Te;  K = 768;  N = 2304; tt = bid; }
        else if (bid < 576)  { W = Wo;  T = To;  K = 768;  N = 768;  tt = bid - 432; }
        else if (bid < 1152) { W = Wf1; T = Tf1; K = 768;  N = 3072; tt = bid - 576; }
        else                 { W = Wf2; T = Tf2; K = 3072; N = 768;  tt = bid - 1152; }
        int nx = N >> 6;
        int n0 = (tt % nx) * 64, k0 = (tt / nx) * 64;
        int cx = (t & 15) * 4, ry = t >> 4;           // cx: n-chunk, ry: k-row base
#pragma unroll
        for (int i = 0; i < 4; ++i) {
            int r = ry + 16 * i;
            float4 v = *(const float4*)(W + (size_t)(k0 + r) * N + n0 + cx);
            shm[r * 69 + cx + 0] = v.x; shm[r * 69 + cx + 1] = v.y;
            shm[r * 69 + cx + 2] = v.z; shm[r * 69 + cx + 3] = v.w;
        }
        __syncthreads();
        int kc = (t & 15) * 4, ny = t >> 4;           // kc: k-chunk, ny: n-row base
#pragma unroll
        for (int i = 0; i < 4; ++i) {
            int nr = ny + 16 * i;
            bf16x4 o;
#pragma unroll
            for (int j = 0; j < 4; ++j)
                o[j] = (__bf16)shm[(kc + j) * 69 + nr];
            *(bf16x4*)(T + (size_t)(n0 + nr) * K + k0 + kc) = o;
        }
    } else {
        int row = bid - 1728;
        size_t ro = (size_t)row * Dc;
        float4 v;
        float s1 = 0.0f, s2 = 0.0f;
        if (t < 192) {
            v = *(const float4*)(x + ro + t * 4);
            s1 = v.x + v.y + v.z + v.w;
            s2 = v.x * v.x + v.y * v.y + v.z * v.z + v.w * v.w;
#pragma unroll
            for (int o = 32; o; o >>= 1) {
                s1 += __shfl_down(s1, o);
                s2 += __shfl_down(s2, o);
            }
            if ((t & 63) == 0) { shm[t >> 6] = s1; shm[3 + (t >> 6)] = s2; }
        }
        __syncthreads();
        if (t < 192) {
            float S1 = shm[0] + shm[1] + shm[2];
            float S2 = shm[3] + shm[4] + shm[5];
            float mean = S1 * (1.0f / Dc);
            float var = S2 * (1.0f / Dc) - mean * mean;
            float rs = rsqrtf(var + 1e-5f);
            const float4 w4 = *(const float4*)(lw + t * 4);
            const float4 b4 = *(const float4*)(lb + t * 4);
            bf16x4 o;
            o[0] = (__bf16)((v.x - mean) * rs * w4.x + b4.x);
            o[1] = (__bf16)((v.y - mean) * rs * w4.y + b4.y);
            o[2] = (__bf16)((v.z - mean) * rs * w4.z + b4.z);
            o[3] = (__bf16)((v.w - mean) * rs * w4.w + b4.w);
            *(bf16x4*)(outb + ro + t * 4) = o;
        }
    }
}

// =====================================================================
// LN2: f32 in -> bf16 out + f32 out, 192 threads (float4 per thread)
__global__ __launch_bounds__(192) void ln2_kernel(const float* __restrict__ x,
                                                  const float* __restrict__ lw,
                                                  const float* __restrict__ lb,
                                                  __bf16* __restrict__ outb,
                                                  float* __restrict__ outf) {
    __shared__ float red[6];
    int row = blockIdx.x;
    size_t ro = (size_t)row * Dc;
    int t = threadIdx.x;
    float4 v = *(const float4*)(x + ro + t * 4);
    float s1 = v.x + v.y + v.z + v.w;
    float s2 = v.x * v.x + v.y * v.y + v.z * v.z + v.w * v.w;
#pragma unroll
    for (int o = 32; o; o >>= 1) {
        s1 += __shfl_down(s1, o);
        s2 += __shfl_down(s2, o);
    }
    if ((t & 63) == 0) { red[t >> 6] = s1; red[3 + (t >> 6)] = s2; }
    __syncthreads();
    float S1 = red[0] + red[1] + red[2];
    float S2 = red[3] + red[4] + red[5];
    float mean = S1 * (1.0f / Dc);
    float var = S2 * (1.0f / Dc) - mean * mean;
    float rs = rsqrtf(var + 1e-5f);
    const float4 w4 = *(const float4*)(lw + t * 4);
    const float4 b4 = *(const float4*)(lb + t * 4);
    float o0 = (v.x - mean) * rs * w4.x + b4.x;
    float o1 = (v.y - mean) * rs * w4.y + b4.y;
    float o2 = (v.z - mean) * rs * w4.z + b4.z;
    float o3 = (v.w - mean) * rs * w4.w + b4.w;
    bf16x4 ob; ob[0] = (__bf16)o0; ob[1] = (__bf16)o1; ob[2] = (__bf16)o2; ob[3] = (__bf16)o3;
    *(bf16x4*)(outb + ro + t * 4) = ob;
    *(float4*)(outf + ro + t * 4) = make_float4(o0, o1, o2, o3);
}

// =====================================================================
// bf16 MFMA GEMM, both operands row-major-K (B pre-transposed).
// 3-buffer, 2-deep counted-vmcnt pipeline; both-sides XOR swizzle.
// EPI: 1 = bias + addin -> f32 ; 2 = bias + gelu -> bf16 ; 3 = QKV (bf16 + presents)
template <int BMr, int BNc, int BK, int EPI>
__global__ __launch_bounds__(256) void gemm_bf16(const __bf16* __restrict__ A,
                                                 const __bf16* __restrict__ BT,
                                                 const float* __restrict__ bias,
                                                 const float* __restrict__ addin,
                                                 float* __restrict__ Cf,
                                                 __bf16* __restrict__ Cb,
                                                 float* __restrict__ pres,
                                                 int K, int N) {
    constexpr int HRm = BMr / 32, HRn = BNc / 32;
    constexpr int KS  = BK / 32;
    constexpr int LPR = BK / 8;
    constexpr int SSH = (BK == 32) ? 1 : 0;
    constexpr int IA  = BMr * BK / 2048;
    constexpr int IB  = BNc * BK / 2048;
    constexpr int S1w = IA + IB;
    static_assert(IA * 2048 == BMr * BK && IB * 2048 == BNc * BK, "staging granularity");
    __shared__ __bf16 As[3][BMr * BK];
    __shared__ __bf16 Bs[3][BNc * BK];
    int tid = threadIdx.x;
    int w = tid >> 6, l = tid & 63;
    int wrow = (w >> 1) * (BMr / 2), wcol = (w & 1) * (BNc / 2);
    int brow0 = blockIdx.x * BMr, bcol0 = blockIdx.y * BNc;
    int rsel = l & 15, lg = l >> 4;

    f32x4 acc[HRm][HRn] = {};

    const __bf16* Abase = A + (size_t)brow0 * K;
    const __bf16* Bbase = BT + (size_t)bcol0 * K;

    auto stage = [&](int buf, int kt) {
#pragma unroll
        for (int i = 0; i < IA; ++i) {
            int cid = i * 256 + tid;
            int row = cid / LPR, slot = cid % LPR;
            int chunk = slot ^ ((row >> SSH) & (LPR - 1));
            gload_lds16(Abase + (size_t)row * K + kt + chunk * 8,
                        &As[buf][(i * 256 + w * 64) * 8]);
        }
#pragma unroll
        for (int i = 0; i < IB; ++i) {
            int cid = i * 256 + tid;
            int row = cid / LPR, slot = cid % LPR;
            int chunk = slot ^ ((row >> SSH) & (LPR - 1));
            gload_lds16(Bbase + (size_t)row * K + kt + chunk * 8,
                        &Bs[buf][(i * 256 + w * 64) * 8]);
        }
    };

    int nk = K / BK;
    stage(0, 0);
    stage(1, BK);
    int cur = 0;
    for (int kt = 0; kt < nk; ++kt) {
        if (kt + 2 < nk) {
            int b2 = cur + 2; if (b2 >= 3) b2 -= 3;
            stage(b2, (kt + 2) * BK);
            waitcnt_vm<2 * S1w>();
        } else if (kt + 1 < nk) {
            waitcnt_vm<S1w>();
        } else {
            waitcnt_vm<0>();
        }
        __builtin_amdgcn_s_barrier();
        __builtin_amdgcn_sched_barrier(0);

        bf16x8 af[KS][HRm], bfr[KS][HRn];
#pragma unroll
        for (int m = 0; m < HRm; ++m) {
            int r = wrow + m * 16 + rsel;
            int sw = (r >> SSH) & (LPR - 1);
#pragma unroll
            for (int s = 0; s < KS; ++s)
                af[s][m] = *(const bf16x8*)(&As[cur][r * BK + ((s * 4 + lg) ^ sw) * 8]);
        }
#pragma unroll
        for (int n = 0; n < HRn; ++n) {
            int r = wcol + n * 16 + rsel;
            int sw = (r >> SSH) & (LPR - 1);
#pragma unroll
            for (int s = 0; s < KS; ++s)
                bfr[s][n] = *(const bf16x8*)(&Bs[cur][r * BK + ((s * 4 + lg) ^ sw) * 8]);
        }
#pragma unroll
        for (int s = 0; s < KS; ++s)
#pragma unroll
            for (int m = 0; m < HRm; ++m)
#pragma unroll
                for (int n = 0; n < HRn; ++n)
                    acc[m][n] = __builtin_amdgcn_mfma_f32_16x16x32_bf16(af[s][m], bfr[s][n], acc[m][n], 0, 0, 0);

        __builtin_amdgcn_sched_barrier(0);
        __builtin_amdgcn_s_barrier();
        cur = (cur == 2) ? 0 : cur + 1;
    }

    // epilogue: frag C[row=lg*4+i][col=rsel]
    int r4 = lg * 4, cc = rsel;
#pragma unroll
    for (int m = 0; m < HRm; ++m)
#pragma unroll
        for (int n = 0; n < HRn; ++n) {
            int col = bcol0 + wcol + n * 16 + cc;
            float bv = bias[col];
#pragma unroll
            for (int i = 0; i < 4; ++i) {
                int row = brow0 + wrow + m * 16 + r4 + i;
                float v = acc[m][n][i] + bv;
                if (EPI == 1) {
                    v += addin[(size_t)row * N + col];
                    Cf[(size_t)row * N + col] = v;
                }
                if (EPI == 2) {
                    // gelu(x) = x * sigmoid(2u), u = 0.79788456(x + 0.044715 x^3)
                    float u = 0.7978845608f * (v + 0.044715f * v * v * v);
                    v = v / (1.0f + __expf(-2.0f * u));
                    Cb[(size_t)row * N + col] = (__bf16)v;
                }
                if (EPI == 3) {
                    Cb[(size_t)row * N + col] = (__bf16)v;
                    if (col >= 768) {
                        int kv = (col >= 1536) ? 1 : 0;
                        pres[((size_t)kv * Mtot + row) * Dc + (col - 768 - kv * 768)] = v;
                    }
                }
            }
        }
}

// =====================================================================
// MFMA flash attention. Block = 4 waves, 64 q-rows for one (b,h). bf16 out.
__global__ __launch_bounds__(256) void attn_mfma_kernel(const __bf16* __restrict__ qkvb,
                                                        __bf16* __restrict__ aout) {
    __shared__ __bf16 Ks[64 * 72];
    __shared__ __bf16 Vts[64 * 72];
    __shared__ __bf16 Ps[4][16 * 72];
    int bh = blockIdx.x;
    int b = bh / Hc, h = bh % Hc;
    int qt = (Sc / 64 - 1) - blockIdx.y;
    int tid = threadIdx.x;
    int w = tid >> 6, l = tid & 63;
    int lr = l & 15, lg = l >> 4;
    int qb = qt * 64;

    const __bf16* base = qkvb + (size_t)b * Sc * 2304 + h * 64;

    bf16x8 qf[2];
    {
        const __bf16* qrow = base + (size_t)(qb + w * 16 + lr) * 2304 + lg * 8;
        qf[0] = *(const bf16x8*)(qrow);
        qf[1] = *(const bf16x8*)(qrow + 32);
    }

    f32x4 O[4] = {};
    float mrow[4], lrowv[4];
#pragma unroll
    for (int i = 0; i < 4; ++i) { mrow[i] = -1e30f; lrowv[i] = 0.0f; }

    int kj = tid >> 2, kc = tid & 3;
    int vj = tid & 63, vd0 = (tid >> 6) * 8;

    for (int t = 0; t <= qt; ++t) {
        __syncthreads();
#pragma unroll
        for (int it = 0; it < 2; ++it) {
            int c = kc + 4 * it;
            bf16x8 v = *(const bf16x8*)(base + (size_t)(t * 64 + kj) * 2304 + 768 + c * 8);
            *(bf16x8*)(&Ks[kj * 72 + c * 8]) = v;
        }
#pragma unroll
        for (int it = 0; it < 2; ++it) {
            int d0 = vd0 + 32 * it;
            bf16x8 v = *(const bf16x8*)(base + (size_t)(t * 64 + vj) * 2304 + 1536 + d0);
#pragma unroll
            for (int i = 0; i < 8; ++i)
                Vts[(d0 + i) * 72 + vj] = v[i];
        }
        __syncthreads();

        f32x4 sc[4] = {};
        __builtin_amdgcn_s_setprio(1);
#pragma unroll
        for (int s = 0; s < 2; ++s)
#pragma unroll
            for (int n = 0; n < 4; ++n) {
                bf16x8 kf = *(const bf16x8*)(&Ks[(n * 16 + lr) * 72 + s * 32 + lg * 8]);
                sc[n] = __builtin_amdgcn_mfma_f32_16x16x32_bf16(qf[s], kf, sc[n], 0, 0, 0);
            }
        __builtin_amdgcn_s_setprio(0);

        bool diag = (t == qt);
#pragma unroll
        for (int n = 0; n < 4; ++n)
#pragma unroll
            for (int i = 0; i < 4; ++i) {
                float s = sc[n][i] * 0.125f;
                if (diag) {
                    int jg = n * 16 + lr;
                    int qg = w * 16 + lg * 4 + i;
                    if (jg > qg) s = -1e30f;
                }
                sc[n][i] = s;
            }
        float corr[4], psum[4];
#pragma unroll
        for (int i = 0; i < 4; ++i) {
            float mx = fmaxf(fmaxf(sc[0][i], sc[1][i]), fmaxf(sc[2][i], sc[3][i]));
#pragma unroll
            for (int o = 1; o < 16; o <<= 1) mx = fmaxf(mx, __shfl_xor(mx, o));
            float mnew = fmaxf(mrow[i], mx);
            corr[i] = __expf(mrow[i] - mnew);
            mrow[i] = mnew;
            psum[i] = 0.0f;
        }
#pragma unroll
        for (int n = 0; n < 4; ++n)
#pragma unroll
            for (int i = 0; i < 4; ++i) {
                float p = __expf(sc[n][i] - mrow[i]);
                psum[i] += p;
                Ps[w][(lg * 4 + i) * 72 + n * 16 + lr] = (__bf16)p;
            }
#pragma unroll
        for (int i = 0; i < 4; ++i) {
#pragma unroll
            for (int o = 1; o < 16; o <<= 1) psum[i] += __shfl_xor(psum[i], o);
            lrowv[i] = lrowv[i] * corr[i] + psum[i];
        }
#pragma unroll
        for (int n = 0; n < 4; ++n)
#pragma unroll
            for (int i = 0; i < 4; ++i) O[n][i] *= corr[i];
        __builtin_amdgcn_s_setprio(1);
#pragma unroll
        for (int s = 0; s < 2; ++s) {
            bf16x8 pf = *(const bf16x8*)(&Ps[w][lr * 72 + s * 32 + lg * 8]);
#pragma unroll
            for (int n = 0; n < 4; ++n) {
                bf16x8 vf = *(const bf16x8*)(&Vts[(n * 16 + lr) * 72 + s * 32 + lg * 8]);
                O[n] = __builtin_amdgcn_mfma_f32_16x16x32_bf16(pf, vf, O[n], 0, 0, 0);
            }
        }
        __builtin_amdgcn_s_setprio(0);
    }
    __bf16* orow = aout + (size_t)(b * Sc + qb + w * 16 + lg * 4) * Dc + h * 64 + lr;
#pragma unroll
    for (int n = 0; n < 4; ++n)
#pragma unroll
        for (int i = 0; i < 4; ++i)
            orow[(size_t)i * Dc + n * 16] = (__bf16)(O[n][i] / lrowv[i]);
}

// =====================================================================
extern "C" void kernel_launch(void* const* d_in, const int* in_sizes, int n_in,
                              void* d_out, int out_size, void* d_ws, size_t ws_size,
                              hipStream_t stream) {
    const int*   tokens = (const int*)d_in[0];
    const float* wte    = (const float*)d_in[1];
    const float* wpe    = (const float*)d_in[2];
    const float* ln1_w  = (const float*)d_in[3];
    const float* ln1_b  = (const float*)d_in[4];
    const float* ln2_w  = (const float*)d_in[5];
    const float* ln2_b  = (const float*)d_in[6];
    const float* W_exp  = (const float*)d_in[7];
    const float* b_exp  = (const float*)d_in[8];
    const float* W_o    = (const float*)d_in[9];
    const float* b_o    = (const float*)d_in[10];
    const float* W_ff1  = (const float*)d_in[11];
    const float* b_ff1  = (const float*)d_in[12];
    const float* W_ff2  = (const float*)d_in[13];
    const float* b_ff2  = (const float*)d_in[14];

    float* out_x    = (float*)d_out;
    float* out_pres = out_x + (size_t)Mtot * Dc;

    float* ws   = (float*)d_ws;
    float* x    = ws;                                   // M*D f32 (residual stream)
    float* addf = x + (size_t)Mtot * Dc;                // M*D f32 (LN2 out f32)
    __bf16* hb   = (__bf16*)(addf + (size_t)Mtot * Dc); // M*D bf16 (LN1 out / attn out)
    __bf16* addb = hb + (size_t)Mtot * Dc;              // M*D bf16 (LN2 out bf16)
    __bf16* qkvb = addb + (size_t)Mtot * Dc;            // M*3D bf16
    __bf16* ff1b = qkvb + (size_t)Mtot * 3 * Dc;        // M*FF bf16
    // single-layer transposed bf16 weights (rewritten each layer, L2/L3-warm)
    __bf16* wt_exp = ff1b + (size_t)Mtot * FFc;         // 2304*768
    __bf16* wt_o   = wt_exp + (size_t)2304 * 768;       // 768*768
    __bf16* wt_ff1 = wt_o   + (size_t)768 * 768;        // 3072*768
    __bf16* wt_ff2 = wt_ff1 + (size_t)3072 * 768;       // 768*3072

    embed_kernel<<<Mtot, 256, 0, stream>>>(tokens, wte, wpe, x);

    for (int lidx = 0; lidx < Lc; ++lidx) {
        // fused per-layer prep: 4 weight transposes (64x64 tiles) + LN1
        prep_kernel<<<1728 + Mtot, 256, 0, stream>>>(
            W_exp + (size_t)lidx * 768 * 2304, W_o + (size_t)lidx * 768 * 768,
            W_ff1 + (size_t)lidx * 768 * 3072, W_ff2 + (size_t)lidx * 3072 * 768,
            wt_exp, wt_o, wt_ff1, wt_ff2,
            x, ln1_w + lidx * Dc, ln1_b + lidx * Dc, hb);

        // QKV = hb @ W_exp + b_exp -> qkvb bf16 + presents f32  (768 blocks = 3/CU)
        gemm_bf16<64, 192, 32, 3><<<dim3(Mtot / 64, 2304 / 192), 256, 0, stream>>>(
            hb, wt_exp, b_exp + (size_t)lidx * 3 * Dc,
            nullptr, nullptr, qkvb, out_pres + (size_t)lidx * 2 * Mtot * Dc, 768, 2304);
        // attention -> hb (bf16)
        attn_mfma_kernel<<<dim3(Bc * Hc, Sc / 64), 256, 0, stream>>>(qkvb, hb);
        // x = hb @ W_o + b_o + x  (512 blocks = 2/CU)
        gemm_bf16<64, 96, 64, 1><<<dim3(Mtot / 64, 768 / 96), 256, 0, stream>>>(
            hb, wt_o, b_o + (size_t)lidx * Dc,
            x, x, nullptr, nullptr, 768, 768);
        // LN2 -> addb (bf16) + addf (f32)
        ln2_kernel<<<Mtot, 192, 0, stream>>>(
            x, ln2_w + lidx * Dc, ln2_b + lidx * Dc, addb, addf);
        // ff1 = gelu(addb @ W_ff1 + b_ff1) -> bf16  (128x128, 768 blocks = 3/CU)
        gemm_bf16<128, 128, 32, 2><<<dim3(Mtot / 128, FFc / 128), 256, 0, stream>>>(
            addb, wt_ff1, b_ff1 + (size_t)lidx * FFc,
            nullptr, nullptr, ff1b, nullptr, 768, FFc);
        // x = ff1b @ W_ff2 + b_ff2 + addf ; last layer writes out_x directly
        float* ff2dst = (lidx == Lc - 1) ? out_x : x;
        gemm_bf16<64, 96, 64, 1><<<dim3(Mtot / 64, 768 / 96), 256, 0, stream>>>(
            ff1b, wt_ff2, b_ff2 + (size_t)lidx * Dc,
            addf, ff2dst, nullptr, nullptr, 3072, 768);
    }
}